// Round 1
// 535.769 us; speedup vs baseline: 1.0071x; 1.0071x over previous
//
#include <hip/hip_runtime.h>
#include <stdint.h>

typedef __attribute__((ext_vector_type(8))) short short8;
typedef __attribute__((ext_vector_type(4))) float f32x4;
typedef __attribute__((ext_vector_type(4))) int i32x4;
typedef __attribute__((ext_vector_type(8))) unsigned short ushort8v;

#define NEGINF_F (-1000000.0f)

__device__ __forceinline__ unsigned short f2bf(float f) {
  union { float f; uint32_t u; } v; v.f = f;
  uint32_t r = (v.u + 0x7FFFu + ((v.u >> 16) & 1u)) >> 16;
  return (unsigned short)r;
}
__device__ __forceinline__ void gl_lds16(const void* g, void* l) {
  __builtin_amdgcn_global_load_lds(
      (const __attribute__((address_space(1))) void*)g,
      (__attribute__((address_space(3))) void*)l, 16, 0, 0);
}

// C = A @ B^T, fp32 accum via mfma_f32_16x16x32_bf16. 128x128 tile, BK=32,
// 256 thr = 4 waves (2x2), 4x4 frags/wave. B always bf16 [N x K].
// A32: A is fp32, staged raw to LDS (linear), converted at fragment build.
// OUT32: C is fp32, vectorized LDS-staged epilogue. MASKED: int mask -> NEGINF.
// bf16 LDS tiles use a 16B-chunk XOR swizzle (chunk ^= row&3) applied on the
// *global source address* of global_load_lds (rule #21) and on frag reads:
// breaks the 8-way bank conflict of the 64B row stride down to 4-way.
template<bool A32, bool OUT32, bool MASKED>
__global__ __launch_bounds__(256, 2)
void gemm_nt(const void* __restrict__ Av, const unsigned short* __restrict__ B,
             void* __restrict__ Cv, const int* __restrict__ mask,
             int K, int lda, int ldb, int ldc,
             long sA, long sB, long sC, long sM, float scale)
{
  constexpr int ABYTES = A32 ? 128 * 32 * 4 : 128 * 32 * 2;
  constexpr int BBYTES = 128 * 32 * 2;
  constexpr int SMEM = (ABYTES + BBYTES) > 16384 ? (ABYTES + BBYTES) : 16384;
  __shared__ __align__(16) unsigned char smem[SMEM];
  unsigned char* AsRaw = smem;
  unsigned short* Bs = (unsigned short*)(smem + ABYTES);

  const int t = threadIdx.x;
  const int b = blockIdx.z;
  const float* Af = (const float*)Av + (long)b * sA;
  const unsigned short* Ah = (const unsigned short*)Av + (long)b * sA;
  const unsigned short* Bp = B + (long)b * sB;
  const int* mp = MASKED ? (mask + (long)b * sM) : nullptr;
  const int tm = blockIdx.x * 128;
  const int tn = blockIdx.y * 128;

  const int lane = t & 63, wave = t >> 6;
  const int wm = (wave & 1) * 64, wn = (wave >> 1) * 64;
  const int q = lane >> 4, mr = lane & 15;

  f32x4 acc[4][4];
#pragma unroll
  for (int i = 0; i < 4; i++)
#pragma unroll
    for (int j = 0; j < 4; j++) acc[i][j] = (f32x4){0.f, 0.f, 0.f, 0.f};

  const int r0a = t >> 2;                              // staging row
  const int cswz = ((t & 3) ^ ((t >> 2) & 3)) * 8;     // swizzled k-chunk (shorts)
  const int sw8 = (q ^ (mr & 3)) * 8;                  // frag-read swizzled offset

  for (int k0 = 0; k0 < K; k0 += 32) {
    __syncthreads();
    if (A32) {
      float* Asf = (float*)AsRaw;
#pragma unroll
      for (int rd = 0; rd < 4; rd++) {
        const int f = rd * 1024 + t * 4;       // 4 floats/thread/round
        const int row = f >> 5, col = f & 31;
        gl_lds16(Af + (long)(tm + row) * lda + k0 + col, Asf + f);
      }
    } else {
      unsigned short* Ash = (unsigned short*)AsRaw;
      const unsigned short* ga = Ah + (long)(tm + r0a) * lda + k0 + cswz;
      gl_lds16(ga, &Ash[(size_t)t * 8]);
      gl_lds16(ga + (long)64 * lda, &Ash[(size_t)(t + 256) * 8]);
    }
    {
      const unsigned short* gb = Bp + (long)(tn + r0a) * ldb + k0 + cswz;
      gl_lds16(gb, &Bs[(size_t)t * 8]);
      gl_lds16(gb + (long)64 * ldb, &Bs[(size_t)(t + 256) * 8]);
    }
    __syncthreads();

    short8 af[4], bfr[4];
#pragma unroll
    for (int i = 0; i < 4; i++) {
      if (A32) {
        const float* Asf = (const float*)AsRaw;
        const int base = (wm + i * 16 + mr) * 32 + q * 8;
        const f32x4 x0 = *(const f32x4*)&Asf[base];
        const f32x4 x1 = *(const f32x4*)&Asf[base + 4];
        short8 v;
        v[0] = (short)f2bf(x0[0]); v[1] = (short)f2bf(x0[1]);
        v[2] = (short)f2bf(x0[2]); v[3] = (short)f2bf(x0[3]);
        v[4] = (short)f2bf(x1[0]); v[5] = (short)f2bf(x1[1]);
        v[6] = (short)f2bf(x1[2]); v[7] = (short)f2bf(x1[3]);
        af[i] = v;
      } else {
        const unsigned short* Ash = (const unsigned short*)AsRaw;
        af[i] = *(const short8*)&Ash[(size_t)(wm + i * 16 + mr) * 32 + sw8];
      }
      bfr[i] = *(const short8*)&Bs[(size_t)(wn + i * 16 + mr) * 32 + sw8];
    }
#pragma unroll
    for (int i = 0; i < 4; i++)
#pragma unroll
      for (int j = 0; j < 4; j++)
        acc[i][j] = __builtin_amdgcn_mfma_f32_16x16x32_bf16(
            af[i], bfr[j], acc[i][j], 0, 0, 0);
  }

  // C/D layout (m89-verified): col = lane&15, row = (lane>>4)*4 + reg
  if (OUT32) {
    // Vectorized epilogue: stage 32x128 fp32 chunks through LDS (reusing the
    // 16KB staging buffer) with per-row rotate swizzle (col + row*4)&127 so
    // the b128 re-reads spread across all banks; then dwordx4 mask loads and
    // dwordx4 stores, fully coalesced.
    float* ep = (float*)smem;
    float* co = (float*)Cv + (long)b * sC;
    const int band = wm >> 2;                 // 0 or 16 (chunk-local row band)
    const int tr = t >> 3;                    // 0..31 chunk-local row (read)
    const int tcb = (t & 7) * 16;             // logical col base (read)
    const int growb = tm + (tr >> 4) * 64 + (tr & 15);
#pragma unroll
    for (int i = 0; i < 4; i++) {
      __syncthreads();
#pragma unroll
      for (int j = 0; j < 4; j++) {
        const int colb = wn + j * 16 + mr;
#pragma unroll
        for (int r = 0; r < 4; r++) {
          const int lr = band + q * 4 + r;
          ep[lr * 128 + ((colb + lr * 4) & 127)] = acc[i][j][r];
        }
      }
      __syncthreads();
      const int gr = growb + i * 16;
      const long rbase = (long)gr * ldc;
      const float* eprow = ep + tr * 128;
      const int rot = tr * 4;
#pragma unroll
      for (int k = 0; k < 4; k++) {
        const int lc = tcb + k * 4;                 // logical col in tile
        f32x4 x = *(const f32x4*)&eprow[(lc + rot) & 127];
        x *= scale;
        if (MASKED) {
          const i32x4 mv = *(const i32x4*)&mp[rbase + tn + lc];
#pragma unroll
          for (int e = 0; e < 4; e++)
            if (!mv[e]) x[e] = NEGINF_F;
        }
        *(f32x4*)&co[rbase + tn + lc] = x;
      }
    }
  } else {
#pragma unroll
    for (int i = 0; i < 4; i++) {
#pragma unroll
      for (int j = 0; j < 4; j++) {
        const int row0 = tm + wm + i * 16 + q * 4;
        const int col  = tn + wn + j * 16 + mr;
        const f32x4 v = acc[i][j];
#pragma unroll
        for (int r = 0; r < 4; r++) {
          float x = v[r] * scale;
          ((unsigned short*)Cv + (long)b * sC)[(long)(row0 + r) * ldc + col] = f2bf(x);
        }
      }
    }
  }
}

// one block per row of 2048 fp32: max -> sumexp -> normalize, in place.
// Optionally also emits the normalized row as bf16 to Pb (for the PV GEMM).
__global__ __launch_bounds__(256) void softmax_rows_f32(
    float* __restrict__ P, unsigned short* __restrict__ Pb)
{
  const int row = blockIdx.x;
  float* p = P + (size_t)row * 2048;
  const int t = threadIdx.x, lane = t & 63, wv = t >> 6;
  f32x4 a = *(const f32x4*)(p + t * 8);
  f32x4 c = *(const f32x4*)(p + t * 8 + 4);
  float x[8] = {a[0], a[1], a[2], a[3], c[0], c[1], c[2], c[3]};
  float mx = x[0];
#pragma unroll
  for (int j = 1; j < 8; j++) mx = fmaxf(mx, x[j]);
#pragma unroll
  for (int o = 32; o > 0; o >>= 1) mx = fmaxf(mx, __shfl_xor(mx, o));
  __shared__ float rm[4], rs[4];
  if (lane == 0) rm[wv] = mx;
  __syncthreads();
  mx = fmaxf(fmaxf(rm[0], rm[1]), fmaxf(rm[2], rm[3]));
  float e[8], s = 0.f;
#pragma unroll
  for (int j = 0; j < 8; j++) { e[j] = __expf(x[j] - mx); s += e[j]; }
#pragma unroll
  for (int o = 32; o > 0; o >>= 1) s += __shfl_xor(s, o);
  if (lane == 0) rs[wv] = s;
  __syncthreads();
  s = rs[0] + rs[1] + rs[2] + rs[3];
  // fully-masked row: max stays at NEGINF -> reference (softmax * mask) = 0
  const float linv = (mx < -1.0e5f) ? 0.f : 1.f / s;
  f32x4 o0 = {e[0] * linv, e[1] * linv, e[2] * linv, e[3] * linv};
  f32x4 o1 = {e[4] * linv, e[5] * linv, e[6] * linv, e[7] * linv};
  *(f32x4*)(p + t * 8) = o0;
  *(f32x4*)(p + t * 8 + 4) = o1;
  if (Pb) {
    ushort8v ob;
    ob[0] = f2bf(o0[0]); ob[1] = f2bf(o0[1]); ob[2] = f2bf(o0[2]); ob[3] = f2bf(o0[3]);
    ob[4] = f2bf(o1[0]); ob[5] = f2bf(o1[1]); ob[6] = f2bf(o1[2]); ob[7] = f2bf(o1[3]);
    *(ushort8v*)(Pb + (size_t)row * 2048 + t * 8) = ob;
  }
}

// fp32 -> bf16 bulk convert (8388608 elems)
__global__ __launch_bounds__(256) void cvt(
    const float* __restrict__ s, unsigned short* __restrict__ d)
{
  const size_t i = ((size_t)blockIdx.x * 256 + threadIdx.x) * 8;
  const float4 a = *(const float4*)(s + i);
  const float4 b = *(const float4*)(s + i + 4);
  ushort8v o;
  o[0] = f2bf(a.x); o[1] = f2bf(a.y); o[2] = f2bf(a.z); o[3] = f2bf(a.w);
  o[4] = f2bf(b.x); o[5] = f2bf(b.y); o[6] = f2bf(b.z); o[7] = f2bf(b.w);
  *(ushort8v*)(d + i) = o;
}

// per-batch transpose+convert: src[b][s][i] fp32 (2048x512) -> dst[b][i][s] bf16
__global__ __launch_bounds__(256) void cvt_t_v(
    const float* __restrict__ src, unsigned short* __restrict__ dst)
{
  const int b = blockIdx.z;
  __shared__ float tile[32][33];
  const int s0 = blockIdx.x * 32, i0 = blockIdx.y * 32;
  const int tx = threadIdx.x & 31, ty = threadIdx.x >> 5;
#pragma unroll
  for (int r = 0; r < 4; r++) {
    const int srow = ty + r * 8;
    tile[srow][tx] = src[((size_t)b * 2048 + s0 + srow) * 512 + i0 + tx];
  }
  __syncthreads();
#pragma unroll
  for (int r = 0; r < 4; r++) {
    const int irow = ty + r * 8;
    dst[((size_t)b * 512 + i0 + irow) * 2048 + s0 + tx] = f2bf(tile[tx][irow]);
  }
}

// 512x512 transpose + fp32->bf16 (x3 weights) so projections run as NT GEMMs.
__global__ __launch_bounds__(256) void transpose_w(
    const float* __restrict__ W0, const float* __restrict__ W1,
    const float* __restrict__ W2,
    unsigned short* __restrict__ T0, unsigned short* __restrict__ T1,
    unsigned short* __restrict__ T2)
{
  const float* W = blockIdx.z == 0 ? W0 : (blockIdx.z == 1 ? W1 : W2);
  unsigned short* T = blockIdx.z == 0 ? T0 : (blockIdx.z == 1 ? T1 : T2);
  __shared__ float tile[32][33];
  const int bx = blockIdx.x * 32, by = blockIdx.y * 32;
  const int tx = threadIdx.x & 31, ty = threadIdx.x >> 5;
#pragma unroll
  for (int i = 0; i < 4; i++) {
    const int r = ty + i * 8;
    tile[r][tx] = W[(size_t)(by + r) * 512 + bx + tx];
  }
  __syncthreads();
#pragma unroll
  for (int i = 0; i < 4; i++) {
    const int r = ty + i * 8;
    T[(size_t)(bx + r) * 512 + by + tx] = f2bf(tile[tx][r]);
  }
}

extern "C" void kernel_launch(void* const* d_in, const int* in_sizes, int n_in,
                              void* d_out, int out_size, void* d_ws, size_t ws_size,
                              hipStream_t stream) {
  const float* Xq = (const float*)d_in[0];
  const float* Xk = (const float*)d_in[1];
  const float* Xv = (const float*)d_in[2];
  const int*   mk = (const int*)d_in[3];
  const float* Wq = (const float*)d_in[4];
  const float* Wk = (const float*)d_in[5];
  const float* Wv = (const float*)d_in[6];

  float* z = (float*)d_out;                          // [8,2048,512] fp32
  float* P = z + (size_t)8 * 2048 * 512;             // [8,2048,2048] fp32

  // ws (bf16 elems): 3x Wt + buf1 + buf2 + Ks; Pb (bf16 P', 33.5M elems)
  // overlays Ks (dead after the scores GEMM) and extends beyond it.
  unsigned short* w    = (unsigned short*)d_ws;
  unsigned short* Wtq  = w;
  unsigned short* Wtk  = w + 262144;
  unsigned short* Wtv  = w + 524288;
  unsigned short* buf1 = w + 786432;                 // 8388608 elems
  unsigned short* buf2 = buf1 + 8388608;
  unsigned short* Ks   = buf2 + 8388608;
  unsigned short* Pb   = Ks;                         // overlay, needs 33554432 elems
  // shorts: 786432 + 8388608 + 8388608 + 33554432 = 51118080 -> 102236160 B
  const bool use_pb = ws_size >= (size_t)102236160;

  const float inv_scale = 0.21022410381342863f;      // 512^-0.25

  transpose_w<<<dim3(16, 16, 3), 256, 0, stream>>>(Wq, Wk, Wv, Wtq, Wtk, Wtv);

  // Q projection: bf16(Xq) @ Wq -> buf2 (Qs bf16, scaled)
  cvt<<<dim3(4096), 256, 0, stream>>>(Xq, buf1);
  gemm_nt<false, false, false><<<dim3(128, 4, 1), 256, 0, stream>>>(
      buf1, Wtq, buf2, nullptr, 512, 512, 512, 512, 0, 0, 0, 0, inv_scale);

  // K projection -> Ks (bf16, scaled)
  cvt<<<dim3(4096), 256, 0, stream>>>(Xk, buf1);
  gemm_nt<false, false, false><<<dim3(128, 4, 1), 256, 0, stream>>>(
      buf1, Wtk, Ks, nullptr, 512, 512, 512, 512, 0, 0, 0, 0, inv_scale);

  // Scores: per batch Qs_b @ Ks_b^T, mask epilogue -> P (fp32 logits in d_out)
  gemm_nt<false, true, true><<<dim3(16, 16, 8), 256, 0, stream>>>(
      buf2, Ks, P, mk, 512, 512, 512, 2048,
      1048576, 1048576, 4194304, 4194304, 1.0f);

  softmax_rows_f32<<<dim3(16384), 256, 0, stream>>>(P, use_pb ? Pb : nullptr);

  // z = (P @ Xv) @ Wv  (associativity: V never materialized)
  cvt_t_v<<<dim3(64, 16, 8), 256, 0, stream>>>(Xv, buf1);   // Xvt[b][i][s] bf16
  // T1[b][q][i] = sum_s P[b][q][s] * Xvt[b][i][s]
  if (use_pb) {
    // fast path: A is bf16 P' (normalized), standard staging + swizzle
    gemm_nt<false, false, false><<<dim3(16, 4, 8), 256, 0, stream>>>(
        Pb, buf1, buf2, nullptr, 2048, 2048, 2048, 512,
        4194304, 1048576, 1048576, 0, 1.0f);
  } else {
    // fallback: A is fp32 P from d_out (A32 staging)
    gemm_nt<true, false, false><<<dim3(16, 4, 8), 256, 0, stream>>>(
        P, buf1, buf2, nullptr, 2048, 2048, 2048, 512,
        4194304, 1048576, 1048576, 0, 1.0f);
  }
  // z[q][e] = sum_i T1[q][i] * Wtv[e][i]  (fp32 out)
  gemm_nt<false, true, false><<<dim3(128, 4, 1), 256, 0, stream>>>(
      buf2, Wtv, z, nullptr, 512, 512, 512, 512, 0, 0, 0, 0, 1.0f);
}

// Round 2
// 519.452 us; speedup vs baseline: 1.0388x; 1.0314x over previous
//
#include <hip/hip_runtime.h>
#include <stdint.h>

typedef __attribute__((ext_vector_type(8))) short short8;
typedef __attribute__((ext_vector_type(4))) float f32x4;
typedef __attribute__((ext_vector_type(4))) int i32x4;
typedef __attribute__((ext_vector_type(8))) unsigned short ushort8v;

#define NEGINF_F (-1000000.0f)

__device__ __forceinline__ unsigned short f2bf(float f) {
  union { float f; uint32_t u; } v; v.f = f;
  uint32_t r = (v.u + 0x7FFFu + ((v.u >> 16) & 1u)) >> 16;
  return (unsigned short)r;
}
__device__ __forceinline__ void gl_lds16(const void* g, void* l) {
  __builtin_amdgcn_global_load_lds(
      (const __attribute__((address_space(1))) void*)g,
      (__attribute__((address_space(3))) void*)l, 16, 0, 0);
}

// C = A @ B^T, fp32 accum via mfma_f32_16x16x32_bf16. 128x128 tile, BK=32,
// 256 thr = 4 waves (2x2), 4x4 frags/wave. B always bf16 [N x K].
// A32: A is fp32, staged raw to LDS, converted at fragment build.
// OUT32: C is fp32, vectorized LDS-staged epilogue. MASKED: int mask -> NEGINF.
//
// K-loop is the T3 "minimum 2-phase" pipeline: double-buffered LDS tiles;
// iter t issues global_load_lds for tile t+1 BEFORE the ds_read+MFMA of
// tile t, so HBM->LDS latency hides under compute. One barrier per iter
// (vs 2 in the old stage;barrier;compute structure). The barrier's implicit
// vmcnt(0) drain waits on the *prefetch* (which had the whole compute phase
// in flight) instead of serializing the current tile.
template<bool A32, bool OUT32, bool MASKED>
__global__ __launch_bounds__(256, 2)
void gemm_nt(const void* __restrict__ Av, const unsigned short* __restrict__ B,
             void* __restrict__ Cv, const int* __restrict__ mask,
             int K, int lda, int ldb, int ldc,
             long sA, long sB, long sC, long sM, float scale)
{
  constexpr int ABYTES = A32 ? 128 * 32 * 4 : 128 * 32 * 2;
  constexpr int BBYTES = 128 * 32 * 2;
  constexpr int BUFB = ABYTES + BBYTES;          // 16 KB bf16 / 24 KB A32
  __shared__ __align__(16) unsigned char smem[2 * BUFB];

  const int t = threadIdx.x;
  const int b = blockIdx.z;
  const float* Af = (const float*)Av + (long)b * sA;
  const unsigned short* Ah = (const unsigned short*)Av + (long)b * sA;
  const unsigned short* Bp = B + (long)b * sB;
  const int* mp = MASKED ? (mask + (long)b * sM) : nullptr;
  const int tm = blockIdx.x * 128;
  const int tn = blockIdx.y * 128;

  const int lane = t & 63, wave = t >> 6;
  const int wm = (wave & 1) * 64, wn = (wave >> 1) * 64;
  const int q = lane >> 4, mr = lane & 15;

  f32x4 acc[4][4];
#pragma unroll
  for (int i = 0; i < 4; i++)
#pragma unroll
    for (int j = 0; j < 4; j++) acc[i][j] = (f32x4){0.f, 0.f, 0.f, 0.f};

  const int r0a = t >> 2;                              // staging row
  const int cswz = ((t & 3) ^ ((t >> 2) & 3)) * 8;     // swizzled k-chunk (shorts)
  const int sw8 = (q ^ (mr & 3)) * 8;                  // frag-read swizzled offset

  auto stage = [&](int buf, int k0) {
    unsigned char* base = smem + buf * BUFB;
    if (A32) {
      float* Asf = (float*)base;
#pragma unroll
      for (int rd = 0; rd < 4; rd++) {
        const int f = rd * 1024 + t * 4;       // 4 floats/thread/round
        const int row = f >> 5, col = f & 31;
        gl_lds16(Af + (long)(tm + row) * lda + k0 + col, Asf + f);
      }
    } else {
      unsigned short* Ash = (unsigned short*)base;
      const unsigned short* ga = Ah + (long)(tm + r0a) * lda + k0 + cswz;
      gl_lds16(ga, &Ash[(size_t)t * 8]);
      gl_lds16(ga + (long)64 * lda, &Ash[(size_t)(t + 256) * 8]);
    }
    unsigned short* Bsb = (unsigned short*)(base + ABYTES);
    const unsigned short* gb = Bp + (long)(tn + r0a) * ldb + k0 + cswz;
    gl_lds16(gb, &Bsb[(size_t)t * 8]);
    gl_lds16(gb + (long)64 * ldb, &Bsb[(size_t)(t + 256) * 8]);
  };

  const int nt = K >> 5;
  stage(0, 0);
  __syncthreads();                             // prologue drain (vmcnt 0)

  for (int ti = 0; ti < nt; ++ti) {
    if (ti + 1 < nt) stage((ti + 1) & 1, (ti + 1) << 5);   // prefetch next

    const unsigned char* base = smem + (ti & 1) * BUFB;
    const unsigned short* Bs = (const unsigned short*)(base + ABYTES);
    short8 af[4], bfr[4];
#pragma unroll
    for (int i = 0; i < 4; i++) {
      if (A32) {
        const float* Asf = (const float*)base;
        const int fb = (wm + i * 16 + mr) * 32 + q * 8;
        const f32x4 x0 = *(const f32x4*)&Asf[fb];
        const f32x4 x1 = *(const f32x4*)&Asf[fb + 4];
        short8 v;
        v[0] = (short)f2bf(x0[0]); v[1] = (short)f2bf(x0[1]);
        v[2] = (short)f2bf(x0[2]); v[3] = (short)f2bf(x0[3]);
        v[4] = (short)f2bf(x1[0]); v[5] = (short)f2bf(x1[1]);
        v[6] = (short)f2bf(x1[2]); v[7] = (short)f2bf(x1[3]);
        af[i] = v;
      } else {
        const unsigned short* Ash = (const unsigned short*)base;
        af[i] = *(const short8*)&Ash[(size_t)(wm + i * 16 + mr) * 32 + sw8];
      }
      bfr[i] = *(const short8*)&Bs[(size_t)(wn + i * 16 + mr) * 32 + sw8];
    }
#pragma unroll
    for (int i = 0; i < 4; i++)
#pragma unroll
      for (int j = 0; j < 4; j++)
        acc[i][j] = __builtin_amdgcn_mfma_f32_16x16x32_bf16(
            af[i], bfr[j], acc[i][j], 0, 0, 0);

    if (ti + 1 < nt) __syncthreads();   // waits prefetch (vmcnt0) + frees buf
  }

  // C/D layout (m89-verified): col = lane&15, row = (lane>>4)*4 + reg
  if (OUT32) {
    // Vectorized epilogue: stage 32x128 fp32 chunks through LDS with per-row
    // rotate swizzle (col + row*4)&127, then dwordx4 mask loads + dwordx4
    // stores, fully coalesced.
    float* ep = (float*)smem;
    float* co = (float*)Cv + (long)b * sC;
    const int band = wm >> 2;                 // 0 or 16 (chunk-local row band)
    const int tr = t >> 3;                    // 0..31 chunk-local row (read)
    const int tcb = (t & 7) * 16;             // logical col base (read)
    const int growb = tm + (tr >> 4) * 64 + (tr & 15);
#pragma unroll
    for (int i = 0; i < 4; i++) {
      __syncthreads();
#pragma unroll
      for (int j = 0; j < 4; j++) {
        const int colb = wn + j * 16 + mr;
#pragma unroll
        for (int r = 0; r < 4; r++) {
          const int lr = band + q * 4 + r;
          ep[lr * 128 + ((colb + lr * 4) & 127)] = acc[i][j][r];
        }
      }
      __syncthreads();
      const int gr = growb + i * 16;
      const long rbase = (long)gr * ldc;
      const float* eprow = ep + tr * 128;
      const int rot = tr * 4;
#pragma unroll
      for (int k = 0; k < 4; k++) {
        const int lc = tcb + k * 4;                 // logical col in tile
        f32x4 x = *(const f32x4*)&eprow[(lc + rot) & 127];
        x *= scale;
        if (MASKED) {
          const i32x4 mv = *(const i32x4*)&mp[rbase + tn + lc];
#pragma unroll
          for (int e = 0; e < 4; e++)
            if (!mv[e]) x[e] = NEGINF_F;
        }
        *(f32x4*)&co[rbase + tn + lc] = x;
      }
    }
  } else {
#pragma unroll
    for (int i = 0; i < 4; i++) {
#pragma unroll
      for (int j = 0; j < 4; j++) {
        const int row0 = tm + wm + i * 16 + q * 4;
        const int col  = tn + wn + j * 16 + mr;
        const f32x4 v = acc[i][j];
#pragma unroll
        for (int r = 0; r < 4; r++) {
          float x = v[r] * scale;
          ((unsigned short*)Cv + (long)b * sC)[(long)(row0 + r) * ldc + col] = f2bf(x);
        }
      }
    }
  }
}

// one block per row of 2048 fp32: max -> sumexp -> normalize, in place.
// Optionally also emits the normalized row as bf16 to Pb (for the PV GEMM).
__global__ __launch_bounds__(256) void softmax_rows_f32(
    float* __restrict__ P, unsigned short* __restrict__ Pb)
{
  const int row = blockIdx.x;
  float* p = P + (size_t)row * 2048;
  const int t = threadIdx.x, lane = t & 63, wv = t >> 6;
  f32x4 a = *(const f32x4*)(p + t * 8);
  f32x4 c = *(const f32x4*)(p + t * 8 + 4);
  float x[8] = {a[0], a[1], a[2], a[3], c[0], c[1], c[2], c[3]};
  float mx = x[0];
#pragma unroll
  for (int j = 1; j < 8; j++) mx = fmaxf(mx, x[j]);
#pragma unroll
  for (int o = 32; o > 0; o >>= 1) mx = fmaxf(mx, __shfl_xor(mx, o));
  __shared__ float rm[4], rs[4];
  if (lane == 0) rm[wv] = mx;
  __syncthreads();
  mx = fmaxf(fmaxf(rm[0], rm[1]), fmaxf(rm[2], rm[3]));
  float e[8], s = 0.f;
#pragma unroll
  for (int j = 0; j < 8; j++) { e[j] = __expf(x[j] - mx); s += e[j]; }
#pragma unroll
  for (int o = 32; o > 0; o >>= 1) s += __shfl_xor(s, o);
  if (lane == 0) rs[wv] = s;
  __syncthreads();
  s = rs[0] + rs[1] + rs[2] + rs[3];
  // fully-masked row: max stays at NEGINF -> reference (softmax * mask) = 0
  const float linv = (mx < -1.0e5f) ? 0.f : 1.f / s;
  f32x4 o0 = {e[0] * linv, e[1] * linv, e[2] * linv, e[3] * linv};
  f32x4 o1 = {e[4] * linv, e[5] * linv, e[6] * linv, e[7] * linv};
  *(f32x4*)(p + t * 8) = o0;
  *(f32x4*)(p + t * 8 + 4) = o1;
  if (Pb) {
    ushort8v ob;
    ob[0] = f2bf(o0[0]); ob[1] = f2bf(o0[1]); ob[2] = f2bf(o0[2]); ob[3] = f2bf(o0[3]);
    ob[4] = f2bf(o1[0]); ob[5] = f2bf(o1[1]); ob[6] = f2bf(o1[2]); ob[7] = f2bf(o1[3]);
    *(ushort8v*)(Pb + (size_t)row * 2048 + t * 8) = ob;
  }
}

// fp32 -> bf16 bulk convert (8388608 elems)
__global__ __launch_bounds__(256) void cvt(
    const float* __restrict__ s, unsigned short* __restrict__ d)
{
  const size_t i = ((size_t)blockIdx.x * 256 + threadIdx.x) * 8;
  const float4 a = *(const float4*)(s + i);
  const float4 b = *(const float4*)(s + i + 4);
  ushort8v o;
  o[0] = f2bf(a.x); o[1] = f2bf(a.y); o[2] = f2bf(a.z); o[3] = f2bf(a.w);
  o[4] = f2bf(b.x); o[5] = f2bf(b.y); o[6] = f2bf(b.z); o[7] = f2bf(b.w);
  *(ushort8v*)(d + i) = o;
}

// per-batch transpose+convert: src[b][s][i] fp32 (2048x512) -> dst[b][i][s] bf16
__global__ __launch_bounds__(256) void cvt_t_v(
    const float* __restrict__ src, unsigned short* __restrict__ dst)
{
  const int b = blockIdx.z;
  __shared__ float tile[32][33];
  const int s0 = blockIdx.x * 32, i0 = blockIdx.y * 32;
  const int tx = threadIdx.x & 31, ty = threadIdx.x >> 5;
#pragma unroll
  for (int r = 0; r < 4; r++) {
    const int srow = ty + r * 8;
    tile[srow][tx] = src[((size_t)b * 2048 + s0 + srow) * 512 + i0 + tx];
  }
  __syncthreads();
#pragma unroll
  for (int r = 0; r < 4; r++) {
    const int irow = ty + r * 8;
    dst[((size_t)b * 512 + i0 + irow) * 2048 + s0 + tx] = f2bf(tile[tx][irow]);
  }
}

// 512x512 transpose + fp32->bf16 (x3 weights) so projections run as NT GEMMs.
__global__ __launch_bounds__(256) void transpose_w(
    const float* __restrict__ W0, const float* __restrict__ W1,
    const float* __restrict__ W2,
    unsigned short* __restrict__ T0, unsigned short* __restrict__ T1,
    unsigned short* __restrict__ T2)
{
  const float* W = blockIdx.z == 0 ? W0 : (blockIdx.z == 1 ? W1 : W2);
  unsigned short* T = blockIdx.z == 0 ? T0 : (blockIdx.z == 1 ? T1 : T2);
  __shared__ float tile[32][33];
  const int bx = blockIdx.x * 32, by = blockIdx.y * 32;
  const int tx = threadIdx.x & 31, ty = threadIdx.x >> 5;
#pragma unroll
  for (int i = 0; i < 4; i++) {
    const int r = ty + i * 8;
    tile[r][tx] = W[(size_t)(by + r) * 512 + bx + tx];
  }
  __syncthreads();
#pragma unroll
  for (int i = 0; i < 4; i++) {
    const int r = ty + i * 8;
    T[(size_t)(bx + r) * 512 + by + tx] = f2bf(tile[tx][r]);
  }
}

extern "C" void kernel_launch(void* const* d_in, const int* in_sizes, int n_in,
                              void* d_out, int out_size, void* d_ws, size_t ws_size,
                              hipStream_t stream) {
  const float* Xq = (const float*)d_in[0];
  const float* Xk = (const float*)d_in[1];
  const float* Xv = (const float*)d_in[2];
  const int*   mk = (const int*)d_in[3];
  const float* Wq = (const float*)d_in[4];
  const float* Wk = (const float*)d_in[5];
  const float* Wv = (const float*)d_in[6];

  float* z = (float*)d_out;                          // [8,2048,512] fp32
  float* P = z + (size_t)8 * 2048 * 512;             // [8,2048,2048] fp32

  // ws (bf16 elems): 3x Wt + buf1 + buf2 + Ks; Pb (bf16 P', 33.5M elems)
  // overlays Ks (dead after the scores GEMM) and extends beyond it.
  unsigned short* w    = (unsigned short*)d_ws;
  unsigned short* Wtq  = w;
  unsigned short* Wtk  = w + 262144;
  unsigned short* Wtv  = w + 524288;
  unsigned short* buf1 = w + 786432;                 // 8388608 elems
  unsigned short* buf2 = buf1 + 8388608;
  unsigned short* Ks   = buf2 + 8388608;
  unsigned short* Pb   = Ks;                         // overlay, needs 33554432 elems
  // shorts: 786432 + 8388608 + 8388608 + 33554432 = 51118080 -> 102236160 B
  const bool use_pb = ws_size >= (size_t)102236160;

  const float inv_scale = 0.21022410381342863f;      // 512^-0.25

  transpose_w<<<dim3(16, 16, 3), 256, 0, stream>>>(Wq, Wk, Wv, Wtq, Wtk, Wtv);

  // Q projection: bf16(Xq) @ Wq -> buf2 (Qs bf16, scaled)
  cvt<<<dim3(4096), 256, 0, stream>>>(Xq, buf1);
  gemm_nt<false, false, false><<<dim3(128, 4, 1), 256, 0, stream>>>(
      buf1, Wtq, buf2, nullptr, 512, 512, 512, 512, 0, 0, 0, 0, inv_scale);

  // K projection -> Ks (bf16, scaled)
  cvt<<<dim3(4096), 256, 0, stream>>>(Xk, buf1);
  gemm_nt<false, false, false><<<dim3(128, 4, 1), 256, 0, stream>>>(
      buf1, Wtk, Ks, nullptr, 512, 512, 512, 512, 0, 0, 0, 0, inv_scale);

  // Scores: per batch Qs_b @ Ks_b^T, mask epilogue -> P (fp32 logits in d_out)
  gemm_nt<false, true, true><<<dim3(16, 16, 8), 256, 0, stream>>>(
      buf2, Ks, P, mk, 512, 512, 512, 2048,
      1048576, 1048576, 4194304, 4194304, 1.0f);

  softmax_rows_f32<<<dim3(16384), 256, 0, stream>>>(P, use_pb ? Pb : nullptr);

  // z = (P @ Xv) @ Wv  (associativity: V never materialized)
  cvt_t_v<<<dim3(64, 16, 8), 256, 0, stream>>>(Xv, buf1);   // Xvt[b][i][s] bf16
  // T1[b][q][i] = sum_s P[b][q][s] * Xvt[b][i][s]
  if (use_pb) {
    // fast path: A is bf16 P' (normalized), standard staging + swizzle
    gemm_nt<false, false, false><<<dim3(16, 4, 8), 256, 0, stream>>>(
        Pb, buf1, buf2, nullptr, 2048, 2048, 2048, 512,
        4194304, 1048576, 1048576, 0, 1.0f);
  } else {
    // fallback: A is fp32 P from d_out (A32 staging)
    gemm_nt<true, false, false><<<dim3(16, 4, 8), 256, 0, stream>>>(
        P, buf1, buf2, nullptr, 2048, 2048, 2048, 512,
        4194304, 1048576, 1048576, 0, 1.0f);
  }
  // z[q][e] = sum_i T1[q][i] * Wtv[e][i]  (fp32 out)
  gemm_nt<false, true, false><<<dim3(128, 4, 1), 256, 0, stream>>>(
      buf2, Wtv, z, nullptr, 512, 512, 512, 512, 0, 0, 0, 0, 1.0f);
}

// Round 3
// 519.093 us; speedup vs baseline: 1.0395x; 1.0007x over previous
//
#include <hip/hip_runtime.h>
#include <stdint.h>

typedef __attribute__((ext_vector_type(8))) short short8;
typedef __attribute__((ext_vector_type(4))) float f32x4;
typedef __attribute__((ext_vector_type(4))) int i32x4;
typedef __attribute__((ext_vector_type(8))) unsigned short ushort8v;

#define NEGINF_F (-1000000.0f)

__device__ __forceinline__ unsigned short f2bf(float f) {
  union { float f; uint32_t u; } v; v.f = f;
  uint32_t r = (v.u + 0x7FFFu + ((v.u >> 16) & 1u)) >> 16;
  return (unsigned short)r;
}
__device__ __forceinline__ void gl_lds16(const void* g, void* l) {
  __builtin_amdgcn_global_load_lds(
      (const __attribute__((address_space(1))) void*)g,
      (__attribute__((address_space(3))) void*)l, 16, 0, 0);
}

// C = A @ B^T, fp32 accum via mfma_f32_16x16x32_bf16. 128x128 tile, BK=32,
// 256 thr = 4 waves (2x2), 4x4 frags/wave. B always bf16 [N x K].
// A32: A is fp32, staged raw to LDS, converted at fragment build.
// OUT32: C is fp32, vectorized LDS-staged epilogue. MASKED: int mask -> NEGINF.
//
// K-loop: T3 minimum-2-phase pipeline (double-buffered LDS, prefetch t+1
// before compute of t, one barrier per iter).
//
// Occupancy: 56 arch VGPR + 64 AGPR = 120 unified regs/wave -> 4 waves/SIMD
// fits the 128-reg budget. min_waves_per_EU=4 requests 4 blocks/CU (LDS cap
// is 5 at 32 KB) -> 50% occupancy for latency cover. A32 keeps 2 (higher
// register pressure from the fp32->bf16 fragment build).
template<bool A32, bool OUT32, bool MASKED>
__global__ __launch_bounds__(256, A32 ? 2 : 4)
void gemm_nt(const void* __restrict__ Av, const unsigned short* __restrict__ B,
             void* __restrict__ Cv, const int* __restrict__ mask,
             int K, int lda, int ldb, int ldc,
             long sA, long sB, long sC, long sM, float scale)
{
  constexpr int ABYTES = A32 ? 128 * 32 * 4 : 128 * 32 * 2;
  constexpr int BBYTES = 128 * 32 * 2;
  constexpr int BUFB = ABYTES + BBYTES;          // 16 KB bf16 / 24 KB A32
  __shared__ __align__(16) unsigned char smem[2 * BUFB];

  const int t = threadIdx.x;
  const int b = blockIdx.z;
  const float* Af = (const float*)Av + (long)b * sA;
  const unsigned short* Ah = (const unsigned short*)Av + (long)b * sA;
  const unsigned short* Bp = B + (long)b * sB;
  const int* mp = MASKED ? (mask + (long)b * sM) : nullptr;
  const int tm = blockIdx.x * 128;
  const int tn = blockIdx.y * 128;

  const int lane = t & 63, wave = t >> 6;
  const int wm = (wave & 1) * 64, wn = (wave >> 1) * 64;
  const int q = lane >> 4, mr = lane & 15;

  f32x4 acc[4][4];
#pragma unroll
  for (int i = 0; i < 4; i++)
#pragma unroll
    for (int j = 0; j < 4; j++) acc[i][j] = (f32x4){0.f, 0.f, 0.f, 0.f};

  const int r0a = t >> 2;                              // staging row
  const int cswz = ((t & 3) ^ ((t >> 2) & 3)) * 8;     // swizzled k-chunk (shorts)
  const int sw8 = (q ^ (mr & 3)) * 8;                  // frag-read swizzled offset

  auto stage = [&](int buf, int k0) {
    unsigned char* base = smem + buf * BUFB;
    if (A32) {
      float* Asf = (float*)base;
#pragma unroll
      for (int rd = 0; rd < 4; rd++) {
        const int f = rd * 1024 + t * 4;       // 4 floats/thread/round
        const int row = f >> 5, col = f & 31;
        gl_lds16(Af + (long)(tm + row) * lda + k0 + col, Asf + f);
      }
    } else {
      unsigned short* Ash = (unsigned short*)base;
      const unsigned short* ga = Ah + (long)(tm + r0a) * lda + k0 + cswz;
      gl_lds16(ga, &Ash[(size_t)t * 8]);
      gl_lds16(ga + (long)64 * lda, &Ash[(size_t)(t + 256) * 8]);
    }
    unsigned short* Bsb = (unsigned short*)(base + ABYTES);
    const unsigned short* gb = Bp + (long)(tn + r0a) * ldb + k0 + cswz;
    gl_lds16(gb, &Bsb[(size_t)t * 8]);
    gl_lds16(gb + (long)64 * ldb, &Bsb[(size_t)(t + 256) * 8]);
  };

  const int nt = K >> 5;
  stage(0, 0);
  __syncthreads();                             // prologue drain (vmcnt 0)

  for (int ti = 0; ti < nt; ++ti) {
    if (ti + 1 < nt) stage((ti + 1) & 1, (ti + 1) << 5);   // prefetch next

    const unsigned char* base = smem + (ti & 1) * BUFB;
    const unsigned short* Bs = (const unsigned short*)(base + ABYTES);
    short8 af[4], bfr[4];
#pragma unroll
    for (int i = 0; i < 4; i++) {
      if (A32) {
        const float* Asf = (const float*)base;
        const int fb = (wm + i * 16 + mr) * 32 + q * 8;
        const f32x4 x0 = *(const f32x4*)&Asf[fb];
        const f32x4 x1 = *(const f32x4*)&Asf[fb + 4];
        short8 v;
        v[0] = (short)f2bf(x0[0]); v[1] = (short)f2bf(x0[1]);
        v[2] = (short)f2bf(x0[2]); v[3] = (short)f2bf(x0[3]);
        v[4] = (short)f2bf(x1[0]); v[5] = (short)f2bf(x1[1]);
        v[6] = (short)f2bf(x1[2]); v[7] = (short)f2bf(x1[3]);
        af[i] = v;
      } else {
        const unsigned short* Ash = (const unsigned short*)base;
        af[i] = *(const short8*)&Ash[(size_t)(wm + i * 16 + mr) * 32 + sw8];
      }
      bfr[i] = *(const short8*)&Bs[(size_t)(wn + i * 16 + mr) * 32 + sw8];
    }
#pragma unroll
    for (int i = 0; i < 4; i++)
#pragma unroll
      for (int j = 0; j < 4; j++)
        acc[i][j] = __builtin_amdgcn_mfma_f32_16x16x32_bf16(
            af[i], bfr[j], acc[i][j], 0, 0, 0);

    if (ti + 1 < nt) __syncthreads();   // waits prefetch (vmcnt0) + frees buf
  }

  // C/D layout (m89-verified): col = lane&15, row = (lane>>4)*4 + reg
  if (OUT32) {
    // Vectorized epilogue: stage 32x128 fp32 chunks through LDS with per-row
    // rotate swizzle (col + row*4)&127, then dwordx4 mask loads + dwordx4
    // stores, fully coalesced.
    float* ep = (float*)smem;
    float* co = (float*)Cv + (long)b * sC;
    const int band = wm >> 2;                 // 0 or 16 (chunk-local row band)
    const int tr = t >> 3;                    // 0..31 chunk-local row (read)
    const int tcb = (t & 7) * 16;             // logical col base (read)
    const int growb = tm + (tr >> 4) * 64 + (tr & 15);
#pragma unroll
    for (int i = 0; i < 4; i++) {
      __syncthreads();
#pragma unroll
      for (int j = 0; j < 4; j++) {
        const int colb = wn + j * 16 + mr;
#pragma unroll
        for (int r = 0; r < 4; r++) {
          const int lr = band + q * 4 + r;
          ep[lr * 128 + ((colb + lr * 4) & 127)] = acc[i][j][r];
        }
      }
      __syncthreads();
      const int gr = growb + i * 16;
      const long rbase = (long)gr * ldc;
      const float* eprow = ep + tr * 128;
      const int rot = tr * 4;
#pragma unroll
      for (int k = 0; k < 4; k++) {
        const int lc = tcb + k * 4;                 // logical col in tile
        f32x4 x = *(const f32x4*)&eprow[(lc + rot) & 127];
        x *= scale;
        if (MASKED) {
          const i32x4 mv = *(const i32x4*)&mp[rbase + tn + lc];
#pragma unroll
          for (int e = 0; e < 4; e++)
            if (!mv[e]) x[e] = NEGINF_F;
        }
        *(f32x4*)&co[rbase + tn + lc] = x;
      }
    }
  } else {
#pragma unroll
    for (int i = 0; i < 4; i++) {
#pragma unroll
      for (int j = 0; j < 4; j++) {
        const int row0 = tm + wm + i * 16 + q * 4;
        const int col  = tn + wn + j * 16 + mr;
        const f32x4 v = acc[i][j];
#pragma unroll
        for (int r = 0; r < 4; r++) {
          float x = v[r] * scale;
          ((unsigned short*)Cv + (long)b * sC)[(long)(row0 + r) * ldc + col] = f2bf(x);
        }
      }
    }
  }
}

// one block per row of 2048 fp32: max -> sumexp -> normalize, in place.
// Optionally also emits the normalized row as bf16 to Pb (for the PV GEMM).
__global__ __launch_bounds__(256) void softmax_rows_f32(
    float* __restrict__ P, unsigned short* __restrict__ Pb)
{
  const int row = blockIdx.x;
  float* p = P + (size_t)row * 2048;
  const int t = threadIdx.x, lane = t & 63, wv = t >> 6;
  f32x4 a = *(const f32x4*)(p + t * 8);
  f32x4 c = *(const f32x4*)(p + t * 8 + 4);
  float x[8] = {a[0], a[1], a[2], a[3], c[0], c[1], c[2], c[3]};
  float mx = x[0];
#pragma unroll
  for (int j = 1; j < 8; j++) mx = fmaxf(mx, x[j]);
#pragma unroll
  for (int o = 32; o > 0; o >>= 1) mx = fmaxf(mx, __shfl_xor(mx, o));
  __shared__ float rm[4], rs[4];
  if (lane == 0) rm[wv] = mx;
  __syncthreads();
  mx = fmaxf(fmaxf(rm[0], rm[1]), fmaxf(rm[2], rm[3]));
  float e[8], s = 0.f;
#pragma unroll
  for (int j = 0; j < 8; j++) { e[j] = __expf(x[j] - mx); s += e[j]; }
#pragma unroll
  for (int o = 32; o > 0; o >>= 1) s += __shfl_xor(s, o);
  if (lane == 0) rs[wv] = s;
  __syncthreads();
  s = rs[0] + rs[1] + rs[2] + rs[3];
  // fully-masked row: max stays at NEGINF -> reference (softmax * mask) = 0
  const float linv = (mx < -1.0e5f) ? 0.f : 1.f / s;
  f32x4 o0 = {e[0] * linv, e[1] * linv, e[2] * linv, e[3] * linv};
  f32x4 o1 = {e[4] * linv, e[5] * linv, e[6] * linv, e[7] * linv};
  *(f32x4*)(p + t * 8) = o0;
  *(f32x4*)(p + t * 8 + 4) = o1;
  if (Pb) {
    ushort8v ob;
    ob[0] = f2bf(o0[0]); ob[1] = f2bf(o0[1]); ob[2] = f2bf(o0[2]); ob[3] = f2bf(o0[3]);
    ob[4] = f2bf(o1[0]); ob[5] = f2bf(o1[1]); ob[6] = f2bf(o1[2]); ob[7] = f2bf(o1[3]);
    *(ushort8v*)(Pb + (size_t)row * 2048 + t * 8) = ob;
  }
}

// dual fp32 -> bf16 bulk convert (2 x 8388608 elems, blockIdx.y selects src)
__global__ __launch_bounds__(256) void cvt2(
    const float* __restrict__ s0, unsigned short* __restrict__ d0,
    const float* __restrict__ s1, unsigned short* __restrict__ d1)
{
  const float* s = blockIdx.y ? s1 : s0;
  unsigned short* d = blockIdx.y ? d1 : d0;
  const size_t i = ((size_t)blockIdx.x * 256 + threadIdx.x) * 8;
  const float4 a = *(const float4*)(s + i);
  const float4 b = *(const float4*)(s + i + 4);
  ushort8v o;
  o[0] = f2bf(a.x); o[1] = f2bf(a.y); o[2] = f2bf(a.z); o[3] = f2bf(a.w);
  o[4] = f2bf(b.x); o[5] = f2bf(b.y); o[6] = f2bf(b.z); o[7] = f2bf(b.w);
  *(ushort8v*)(d + i) = o;
}

// per-batch transpose+convert: src[b][s][i] fp32 (2048x512) -> dst[b][i][s] bf16
__global__ __launch_bounds__(256) void cvt_t_v(
    const float* __restrict__ src, unsigned short* __restrict__ dst)
{
  const int b = blockIdx.z;
  __shared__ float tile[32][33];
  const int s0 = blockIdx.x * 32, i0 = blockIdx.y * 32;
  const int tx = threadIdx.x & 31, ty = threadIdx.x >> 5;
#pragma unroll
  for (int r = 0; r < 4; r++) {
    const int srow = ty + r * 8;
    tile[srow][tx] = src[((size_t)b * 2048 + s0 + srow) * 512 + i0 + tx];
  }
  __syncthreads();
#pragma unroll
  for (int r = 0; r < 4; r++) {
    const int irow = ty + r * 8;
    dst[((size_t)b * 512 + i0 + irow) * 2048 + s0 + tx] = f2bf(tile[tx][irow]);
  }
}

// 512x512 transpose + fp32->bf16 (x3 weights) so projections run as NT GEMMs.
__global__ __launch_bounds__(256) void transpose_w(
    const float* __restrict__ W0, const float* __restrict__ W1,
    const float* __restrict__ W2,
    unsigned short* __restrict__ T0, unsigned short* __restrict__ T1,
    unsigned short* __restrict__ T2)
{
  const float* W = blockIdx.z == 0 ? W0 : (blockIdx.z == 1 ? W1 : W2);
  unsigned short* T = blockIdx.z == 0 ? T0 : (blockIdx.z == 1 ? T1 : T2);
  __shared__ float tile[32][33];
  const int bx = blockIdx.x * 32, by = blockIdx.y * 32;
  const int tx = threadIdx.x & 31, ty = threadIdx.x >> 5;
#pragma unroll
  for (int i = 0; i < 4; i++) {
    const int r = ty + i * 8;
    tile[r][tx] = W[(size_t)(by + r) * 512 + bx + tx];
  }
  __syncthreads();
#pragma unroll
  for (int i = 0; i < 4; i++) {
    const int r = ty + i * 8;
    T[(size_t)(bx + r) * 512 + by + tx] = f2bf(tile[tx][r]);
  }
}

extern "C" void kernel_launch(void* const* d_in, const int* in_sizes, int n_in,
                              void* d_out, int out_size, void* d_ws, size_t ws_size,
                              hipStream_t stream) {
  const float* Xq = (const float*)d_in[0];
  const float* Xk = (const float*)d_in[1];
  const float* Xv = (const float*)d_in[2];
  const int*   mk = (const int*)d_in[3];
  const float* Wq = (const float*)d_in[4];
  const float* Wk = (const float*)d_in[5];
  const float* Wv = (const float*)d_in[6];

  float* z = (float*)d_out;                          // [8,2048,512] fp32
  float* P = z + (size_t)8 * 2048 * 512;             // [8,2048,2048] fp32

  // ws (bf16 elems): 3x Wt + buf1 + buf2 + Ks; Pb (bf16 P', 33.5M elems)
  // overlays Ks (dead after the scores GEMM) and extends beyond it.
  unsigned short* w    = (unsigned short*)d_ws;
  unsigned short* Wtq  = w;
  unsigned short* Wtk  = w + 262144;
  unsigned short* Wtv  = w + 524288;
  unsigned short* buf1 = w + 786432;                 // 8388608 elems
  unsigned short* buf2 = buf1 + 8388608;
  unsigned short* Ks   = buf2 + 8388608;
  unsigned short* Pb   = Ks;                         // overlay, needs 33554432 elems
  // shorts: 786432 + 8388608 + 8388608 + 33554432 = 51118080 -> 102236160 B
  const bool use_pb = ws_size >= (size_t)102236160;

  // Xk bf16 scratch lives in the P region of d_out (P written only later by
  // the scores GEMM; needs 16.8 MB of P's 134 MB).
  unsigned short* Xkb = (unsigned short*)P;

  const float inv_scale = 0.21022410381342863f;      // 512^-0.25

  transpose_w<<<dim3(16, 16, 3), 256, 0, stream>>>(Wq, Wk, Wv, Wtq, Wtk, Wtv);

  // Xq -> buf1 (bf16), Xk -> Xkb (bf16) in one dual-source launch
  cvt2<<<dim3(4096, 2), 256, 0, stream>>>(Xq, buf1, Xk, Xkb);

  // Q projection: bf16(Xq) @ Wq -> buf2 (Qs bf16, scaled)
  gemm_nt<false, false, false><<<dim3(128, 4, 1), 256, 0, stream>>>(
      buf1, Wtq, buf2, nullptr, 512, 512, 512, 512, 0, 0, 0, 0, inv_scale);

  // K projection -> Ks (bf16, scaled)
  gemm_nt<false, false, false><<<dim3(128, 4, 1), 256, 0, stream>>>(
      Xkb, Wtk, Ks, nullptr, 512, 512, 512, 512, 0, 0, 0, 0, inv_scale);

  // Scores: per batch Qs_b @ Ks_b^T, mask epilogue -> P (fp32 logits in d_out)
  gemm_nt<false, true, true><<<dim3(16, 16, 8), 256, 0, stream>>>(
      buf2, Ks, P, mk, 512, 512, 512, 2048,
      1048576, 1048576, 4194304, 4194304, 1.0f);

  softmax_rows_f32<<<dim3(16384), 256, 0, stream>>>(P, use_pb ? Pb : nullptr);

  // z = (P @ Xv) @ Wv  (associativity: V never materialized)
  cvt_t_v<<<dim3(64, 16, 8), 256, 0, stream>>>(Xv, buf1);   // Xvt[b][i][s] bf16
  // T1[b][q][i] = sum_s P[b][q][s] * Xvt[b][i][s]
  if (use_pb) {
    // fast path: A is bf16 P' (normalized), standard staging + swizzle
    gemm_nt<false, false, false><<<dim3(16, 4, 8), 256, 0, stream>>>(
        Pb, buf1, buf2, nullptr, 2048, 2048, 2048, 512,
        4194304, 1048576, 1048576, 0, 1.0f);
  } else {
    // fallback: A is fp32 P from d_out (A32 staging)
    gemm_nt<true, false, false><<<dim3(16, 4, 8), 256, 0, stream>>>(
        P, buf1, buf2, nullptr, 2048, 2048, 2048, 512,
        4194304, 1048576, 1048576, 0, 1.0f);
  }
  // z[q][e] = sum_i T1[q][i] * Wtv[e][i]  (fp32 out)
  gemm_nt<false, true, false><<<dim3(128, 4, 1), 256, 0, stream>>>(
      buf2, Wtv, z, nullptr, 512, 512, 512, 512, 0, 0, 0, 0, 1.0f);
}